// Round 6
// baseline (447.802 us; speedup 1.0000x reference)
//
#include <hip/hip_runtime.h>
#include <hip/hip_bf16.h>
#include <math.h>

#define NN 50000
#define NPAD 50048            // 1564 chunks of 32 rows
#define NE 800000
#define DD 128
#define NCLS 10
#define SCAN_BLOCK 1024
#define NTILES ((NN + 1 + SCAN_BLOCK - 1) / SCAN_BLOCK)  // 49

typedef short s16x8 __attribute__((ext_vector_type(8)));
typedef float f32x4 __attribute__((ext_vector_type(4)));

__device__ __forceinline__ unsigned short f2bf(float x) {
  __hip_bfloat16 h = __float2bfloat16(x);
  return __builtin_bit_cast(unsigned short, h);
}
__device__ __forceinline__ float bflo(unsigned int u) { return __uint_as_float(u << 16); }
__device__ __forceinline__ float bfhi(unsigned int u) { return __uint_as_float(u & 0xFFFF0000u); }

// ---- monotonic float<->uint key for atomic max over floats ----
__device__ __forceinline__ unsigned int fkey(float f) {
  unsigned int u = __float_as_uint(f);
  return u ^ ((u & 0x80000000u) ? 0xFFFFFFFFu : 0x80000000u);
}
__device__ __forceinline__ float funkey(unsigned int k) {
  unsigned int u = (k & 0x80000000u) ? (k ^ 0x80000000u) : ~k;
  return __uint_as_float(u);
}

// ---- CSR build ----
__global__ void k_count(const int* __restrict__ edst, int* __restrict__ offs) {
  int e = blockIdx.x * blockDim.x + threadIdx.x;
  if (e < NE) atomicAdd(&offs[edst[e] + 1], 1);
}

__global__ void k_scan_partial(const int* __restrict__ offs, int* __restrict__ bsum) {
  __shared__ int red[SCAN_BLOCK];
  int i = blockIdx.x * SCAN_BLOCK + threadIdx.x;
  red[threadIdx.x] = (i < NN + 1) ? offs[i] : 0;
  __syncthreads();
  for (int off = SCAN_BLOCK / 2; off > 0; off >>= 1) {
    if ((int)threadIdx.x < off) red[threadIdx.x] += red[threadIdx.x + off];
    __syncthreads();
  }
  if (threadIdx.x == 0) bsum[blockIdx.x] = red[0];
}

__global__ void k_scan_bsum(int* __restrict__ bsum) {
  if (threadIdx.x == 0) {
    int run = 0;
    for (int i = 0; i < NTILES; ++i) { int v = bsum[i]; bsum[i] = run; run += v; }
  }
}

__global__ void k_scan_final(int* __restrict__ offs, const int* __restrict__ bsum,
                             int* __restrict__ cursor) {
  __shared__ int tmp[SCAN_BLOCK];
  int i = blockIdx.x * SCAN_BLOCK + threadIdx.x;
  int v = (i < NN + 1) ? offs[i] : 0;
  tmp[threadIdx.x] = v;
  __syncthreads();
  for (int off = 1; off < SCAN_BLOCK; off <<= 1) {
    int t = ((int)threadIdx.x >= off) ? tmp[threadIdx.x - off] : 0;
    __syncthreads();
    tmp[threadIdx.x] += t;
    __syncthreads();
  }
  int incl = tmp[threadIdx.x] + bsum[blockIdx.x];
  if (i < NN + 1) {
    offs[i] = incl;
    if (i < NN) cursor[i] = incl;
  }
}

__global__ void k_fill(const int* __restrict__ esrc, const int* __restrict__ edst,
                       const float* __restrict__ ew, int* __restrict__ cursor,
                       int2* __restrict__ csr) {
  int e = blockIdx.x * blockDim.x + threadIdx.x;
  if (e < NE) {
    int d = edst[e];
    int p = atomicAdd(&cursor[d], 1);
    csr[p] = make_int2(esrc[e], __float_as_int(ew[e]));
  }
}

// ---- convert W1..3 -> transposed bf16 WT[c][k]; also zero omax ----
__global__ __launch_bounds__(256) void k_cvtW(const float* __restrict__ W1,
    const float* __restrict__ W2, const float* __restrict__ W3,
    unsigned short* __restrict__ WT1, unsigned short* __restrict__ WT2,
    unsigned short* __restrict__ WT3, unsigned int* __restrict__ omax) {
  int i = blockIdx.x * 256 + threadIdx.x;
  if (i < 3 * DD) omax[i] = 0u;
  if (i < DD * DD) {
    int k = i >> 7, c = i & 127;
    WT1[c * DD + k] = f2bf(W1[i]);
    WT2[c * DD + k] = f2bf(W2[i]);
    WT3[c * DD + k] = f2bf(W3[i]);
  }
}

// ---- MFMA GEMM, LDS-staged: S[r][c] = sum_k H[r][k] W[k][c] ----
// block = 256 thr (4 waves), tile = 32 rows x 128 cols. grid = NPAD/32.
// LDS tile swizzled: 16B granule at byte B stored at B ^ ((row&7)<<4).
template <int F32IN>
__global__ __launch_bounds__(256) void k_mm(const void* __restrict__ Hv,
                                            const unsigned short* __restrict__ Wt,
                                            unsigned short* __restrict__ S) {
  __shared__ unsigned short Hl[32 * DD];   // 8 KB, byte-addressed below
  char* lb = (char*)Hl;
  const int wave = threadIdx.x >> 6, lane = threadIdx.x & 63;
  const int l15 = lane & 15, lk16 = (lane >> 4);   // lk = lk16*8 elems
  const int r0 = blockIdx.x * 32;

#pragma unroll
  for (int j = 0; j < 2; ++j) {
    const int idx = threadIdx.x + j * 256;     // 0..511 granules of 16B
    const int B = idx * 16;
    const int row = B >> 8;
    const int addr = B ^ ((row & 7) << 4);
    if (F32IN) {
      const float* H = (const float*)Hv;
      const int r = r0 + row;
      float4 a = make_float4(0.f, 0.f, 0.f, 0.f), b = a;
      if (r < NN) {
        const float* src = H + (size_t)r * DD + ((B & 255) >> 1);
        a = *(const float4*)src;
        b = *(const float4*)(src + 4);
      }
      uint4 pv;
      pv.x = (uint)f2bf(a.x) | ((uint)f2bf(a.y) << 16);
      pv.y = (uint)f2bf(a.z) | ((uint)f2bf(a.w) << 16);
      pv.z = (uint)f2bf(b.x) | ((uint)f2bf(b.y) << 16);
      pv.w = (uint)f2bf(b.z) | ((uint)f2bf(b.w) << 16);
      *(uint4*)(lb + addr) = pv;
    } else {
      const char* H = (const char*)Hv;
      uint4 v = *(const uint4*)(H + (size_t)r0 * 256 + B);
      *(uint4*)(lb + addr) = v;
    }
  }
  __syncthreads();

  const int cbase = wave * 32;
  s16x8 Af[2][4];
#pragma unroll
  for (int m = 0; m < 2; ++m)
#pragma unroll
    for (int ks = 0; ks < 4; ++ks)
      Af[m][ks] = *(const s16x8*)&Wt[(cbase + m * 16 + l15) * DD + ks * 32 + lk16 * 8];

  s16x8 Bf[2][4];
#pragma unroll
  for (int n = 0; n < 2; ++n) {
    const int row = n * 16 + l15;
#pragma unroll
    for (int ks = 0; ks < 4; ++ks) {
      const int B = row * 256 + ks * 64 + lk16 * 16;
      Bf[n][ks] = *(const s16x8*)(lb + (B ^ ((row & 7) << 4)));
    }
  }

  f32x4 acc[2][2];
#pragma unroll
  for (int m = 0; m < 2; ++m)
#pragma unroll
    for (int n = 0; n < 2; ++n) acc[m][n] = (f32x4){0.f, 0.f, 0.f, 0.f};

#pragma unroll
  for (int ks = 0; ks < 4; ++ks)
#pragma unroll
    for (int m = 0; m < 2; ++m)
#pragma unroll
      for (int n = 0; n < 2; ++n)
        acc[m][n] = __builtin_amdgcn_mfma_f32_16x16x32_bf16(Af[m][ks], Bf[n][ks],
                                                            acc[m][n], 0, 0, 0);

  __syncthreads();
#pragma unroll
  for (int m = 0; m < 2; ++m)
#pragma unroll
    for (int n = 0; n < 2; ++n) {
      const int row = n * 16 + l15;
      const int colb = (cbase + m * 16 + 4 * lk16) * 2;
      const int B = row * 256 + colb;
      uint2 pv;
      pv.x = (uint)f2bf(acc[m][n][0]) | ((uint)f2bf(acc[m][n][1]) << 16);
      pv.y = (uint)f2bf(acc[m][n][2]) | ((uint)f2bf(acc[m][n][3]) << 16);
      *(uint2*)(lb + (B ^ ((row & 7) << 4))) = pv;
    }
  __syncthreads();
#pragma unroll
  for (int j = 0; j < 2; ++j) {
    const int idx = threadIdx.x + j * 256;
    const int B = idx * 16;
    const int row = B >> 8;
    uint4 v = *(const uint4*)(lb + (B ^ ((row & 7) << 4)));
    *(uint4*)((char*)S + (size_t)r0 * 256 + B) = v;
  }
}

// ---- aggregation: dual-node, per-quad predicated gathers (no serial tail) ----
// wave = 4 quads x 16 lanes; quad q owns edge slot q; lane t covers cols t*8..t*8+7.
// Each wave processes nodes dA=d0, dB=d0+1 concurrently: up to 8 predicated
// wave-wide gathers in flight per iteration (4 per node).
__device__ __forceinline__ void fma8(float* acc, float w, uint4 u) {
  acc[0] = fmaf(w, bflo(u.x), acc[0]);
  acc[1] = fmaf(w, bfhi(u.x), acc[1]);
  acc[2] = fmaf(w, bflo(u.y), acc[2]);
  acc[3] = fmaf(w, bfhi(u.y), acc[3]);
  acc[4] = fmaf(w, bflo(u.z), acc[4]);
  acc[5] = fmaf(w, bfhi(u.z), acc[5]);
  acc[6] = fmaf(w, bflo(u.w), acc[6]);
  acc[7] = fmaf(w, bfhi(u.w), acc[7]);
}

__global__ __launch_bounds__(256) void k_agg(const unsigned short* __restrict__ S,
                                             const int2* __restrict__ csr,
                                             const int* __restrict__ offs,
                                             const float* __restrict__ bias,
                                             unsigned short* __restrict__ Xout,  // may be null
                                             unsigned int* __restrict__ omax,
                                             int do_relu) {
  __shared__ unsigned int cmax[DD];
  for (int i = threadIdx.x; i < DD; i += 256) cmax[i] = 0u;
  __syncthreads();
  const int lane = threadIdx.x & 63;
  const int wave = threadIdx.x >> 6;
  const int q = lane >> 4;
  const int t = lane & 15;
  const int gwave = blockIdx.x * 4 + wave;
  const int nwaves = gridDim.x * 4;
  const unsigned short* Scol = S + t * 8;

  float bcol[8];
  {
    float4 b0 = *(const float4*)&bias[t * 8];
    float4 b1 = *(const float4*)&bias[t * 8 + 4];
    bcol[0] = b0.x; bcol[1] = b0.y; bcol[2] = b0.z; bcol[3] = b0.w;
    bcol[4] = b1.x; bcol[5] = b1.y; bcol[6] = b1.z; bcol[7] = b1.w;
  }
  float mx[8];
#pragma unroll
  for (int j = 0; j < 8; ++j) mx[j] = -INFINITY;

  // NN is even: dB = d0+1 always valid.
  for (int d0 = gwave * 2; d0 < NN; d0 += nwaves * 2) {
    const int oA = offs[d0];
    const int oM = offs[d0 + 1];     // end of A == start of B
    const int oE = offs[d0 + 2];
    int eA = oA + q; const int eA1 = oM;
    int eB = oM + q; const int eB1 = oE;
    float accA[8] = {0.f, 0.f, 0.f, 0.f, 0.f, 0.f, 0.f, 0.f};
    float accB[8] = {0.f, 0.f, 0.f, 0.f, 0.f, 0.f, 0.f, 0.f};

    while (__any((eA < eA1) || (eB < eB1))) {
      const bool pa0 = eA < eA1,      pa1 = eA + 4 < eA1;
      const bool pa2 = eA + 8 < eA1,  pa3 = eA + 12 < eA1;
      const bool pb0 = eB < eB1,      pb1 = eB + 4 < eB1;
      const bool pb2 = eB + 8 < eB1,  pb3 = eB + 12 < eB1;
      int2 a0, a1, a2, a3, b0, b1, b2, b3;
      if (pa0) a0 = csr[eA];
      if (pa1) a1 = csr[eA + 4];
      if (pa2) a2 = csr[eA + 8];
      if (pa3) a3 = csr[eA + 12];
      if (pb0) b0 = csr[eB];
      if (pb1) b1 = csr[eB + 4];
      if (pb2) b2 = csr[eB + 8];
      if (pb3) b3 = csr[eB + 12];
      uint4 uA0, uA1, uA2, uA3, uB0, uB1, uB2, uB3;
      if (pa0) uA0 = *(const uint4*)&Scol[(size_t)a0.x * DD];
      if (pa1) uA1 = *(const uint4*)&Scol[(size_t)a1.x * DD];
      if (pa2) uA2 = *(const uint4*)&Scol[(size_t)a2.x * DD];
      if (pa3) uA3 = *(const uint4*)&Scol[(size_t)a3.x * DD];
      if (pb0) uB0 = *(const uint4*)&Scol[(size_t)b0.x * DD];
      if (pb1) uB1 = *(const uint4*)&Scol[(size_t)b1.x * DD];
      if (pb2) uB2 = *(const uint4*)&Scol[(size_t)b2.x * DD];
      if (pb3) uB3 = *(const uint4*)&Scol[(size_t)b3.x * DD];
      if (pa0) fma8(accA, __int_as_float(a0.y), uA0);
      if (pa1) fma8(accA, __int_as_float(a1.y), uA1);
      if (pa2) fma8(accA, __int_as_float(a2.y), uA2);
      if (pa3) fma8(accA, __int_as_float(a3.y), uA3);
      if (pb0) fma8(accB, __int_as_float(b0.y), uB0);
      if (pb1) fma8(accB, __int_as_float(b1.y), uB1);
      if (pb2) fma8(accB, __int_as_float(b2.y), uB2);
      if (pb3) fma8(accB, __int_as_float(b3.y), uB3);
      eA += 16; eB += 16;
    }

    // cross-quad butterfly reduce (totals land in ALL lanes) + finalize
#pragma unroll
    for (int j = 0; j < 8; ++j) {
      accA[j] += __shfl_xor(accA[j], 16, 64);
      accA[j] += __shfl_xor(accA[j], 32, 64);
      accA[j] += bcol[j];
      accB[j] += __shfl_xor(accB[j], 16, 64);
      accB[j] += __shfl_xor(accB[j], 32, 64);
      accB[j] += bcol[j];
      if (do_relu) {
        accA[j] = fmaxf(accA[j], 0.f);
        accB[j] = fmaxf(accB[j], 0.f);
      }
      mx[j] = fmaxf(mx[j], fmaxf(accA[j], accB[j]));
    }
    if (Xout) {
      if (q == 0) {
        uint4 xv;
        xv.x = (uint)f2bf(accA[0]) | ((uint)f2bf(accA[1]) << 16);
        xv.y = (uint)f2bf(accA[2]) | ((uint)f2bf(accA[3]) << 16);
        xv.z = (uint)f2bf(accA[4]) | ((uint)f2bf(accA[5]) << 16);
        xv.w = (uint)f2bf(accA[6]) | ((uint)f2bf(accA[7]) << 16);
        *(uint4*)&Xout[(size_t)d0 * DD + t * 8] = xv;
      } else if (q == 1) {
        uint4 xv;
        xv.x = (uint)f2bf(accB[0]) | ((uint)f2bf(accB[1]) << 16);
        xv.y = (uint)f2bf(accB[2]) | ((uint)f2bf(accB[3]) << 16);
        xv.z = (uint)f2bf(accB[4]) | ((uint)f2bf(accB[5]) << 16);
        xv.w = (uint)f2bf(accB[6]) | ((uint)f2bf(accB[7]) << 16);
        *(uint4*)&Xout[(size_t)(d0 + 1) * DD + t * 8] = xv;
      }
    }
  }
  if (q == 0) {
#pragma unroll
    for (int j = 0; j < 8; ++j) atomicMax(&cmax[t * 8 + j], fkey(mx[j]));
  }
  __syncthreads();
  for (int i = threadIdx.x; i < DD; i += 256) atomicMax(&omax[i], cmax[i]);
}

// ---- head ----
__global__ void k_head(const unsigned int* __restrict__ omax,
                       const float* __restrict__ linW,
                       const float* __restrict__ linb,
                       float* __restrict__ out) {
  __shared__ float o[3 * DD];
  __shared__ float logits[NCLS];
  int t = threadIdx.x;  // block = 384
  if (t < 3 * DD) o[t] = funkey(omax[t]);
  __syncthreads();
  if (t < NCLS) {
    float acc = linb[t];
    for (int j = 0; j < 3 * DD; ++j) acc = fmaf(linW[t * 3 * DD + j], o[j], acc);
    logits[t] = acc;
  }
  __syncthreads();
  if (t == 0) {
    float m = -INFINITY;
    for (int c = 0; c < NCLS; ++c) m = fmaxf(m, logits[c]);
    float s = 0.f;
    for (int c = 0; c < NCLS; ++c) s += expf(logits[c] - m);
    float ls = logf(s);
    for (int c = 0; c < NCLS; ++c) out[c] = logits[c] - m - ls;
  }
}

extern "C" void kernel_launch(void* const* d_in, const int* in_sizes, int n_in,
                              void* d_out, int out_size, void* d_ws, size_t ws_size,
                              hipStream_t stream) {
  const float* x    = (const float*)d_in[0];
  const int*   esrc = (const int*)d_in[1];
  const int*   edst = (const int*)d_in[2];
  const float* ew   = (const float*)d_in[3];
  const float* W1   = (const float*)d_in[4];
  const float* b1   = (const float*)d_in[5];
  const float* W2   = (const float*)d_in[6];
  const float* b2   = (const float*)d_in[7];
  const float* W3   = (const float*)d_in[8];
  const float* b3   = (const float*)d_in[9];
  const float* linW = (const float*)d_in[10];
  const float* linb = (const float*)d_in[11];
  float* out = (float*)d_out;

  size_t off = 0;
  auto alloc = [&](size_t bytes) {
    void* p = (char*)d_ws + off;
    off += (bytes + 255) & ~(size_t)255;
    return p;
  };
  unsigned short* X1   = (unsigned short*)alloc((size_t)NPAD * DD * 2);
  unsigned short* X2   = (unsigned short*)alloc((size_t)NPAD * DD * 2);
  unsigned short* S    = (unsigned short*)alloc((size_t)NPAD * DD * 2);
  unsigned short* WT1  = (unsigned short*)alloc((size_t)DD * DD * 2);
  unsigned short* WT2  = (unsigned short*)alloc((size_t)DD * DD * 2);
  unsigned short* WT3  = (unsigned short*)alloc((size_t)DD * DD * 2);
  int*          offs   = (int*)alloc((NN + 2) * 4);   // +1 pad so offs[NN+1] is readable
  int*          cursor = (int*)alloc(NN * 4);
  int2*         csr    = (int2*)alloc((size_t)NE * 8);
  unsigned int* omax   = (unsigned int*)alloc(3 * DD * 4);
  int*          bsum   = (int*)alloc(NTILES * 4);
  (void)ws_size; (void)n_in; (void)in_sizes; (void)out_size;

  // CSR build (shared by all 3 layers)
  hipMemsetAsync(offs, 0, (NN + 2) * 4, stream);
  k_count<<<(NE + 255) / 256, 256, 0, stream>>>(edst, offs);
  k_scan_partial<<<NTILES, SCAN_BLOCK, 0, stream>>>(offs, bsum);
  k_scan_bsum<<<1, 64, 0, stream>>>(bsum);
  k_scan_final<<<NTILES, SCAN_BLOCK, 0, stream>>>(offs, bsum, cursor);
  k_fill<<<(NE + 255) / 256, 256, 0, stream>>>(esrc, edst, ew, cursor, csr);

  k_cvtW<<<(DD * DD + 255) / 256, 256, 0, stream>>>(W1, W2, W3, WT1, WT2, WT3, omax);

  const int mm_grid = NPAD / 32;  // 1564
  // layer 1 (fp32 x read + convert fused into GEMM staging)
  k_mm<1><<<mm_grid, 256, 0, stream>>>(x, WT1, S);
  k_agg<<<2048, 256, 0, stream>>>(S, csr, offs, b1, X1, omax, 1);
  // layer 2
  k_mm<0><<<mm_grid, 256, 0, stream>>>(X1, WT2, S);
  k_agg<<<2048, 256, 0, stream>>>(S, csr, offs, b2, X2, omax + DD, 1);
  // layer 3 (no X store, no relu)
  k_mm<0><<<mm_grid, 256, 0, stream>>>(X2, WT3, S);
  k_agg<<<2048, 256, 0, stream>>>(S, csr, offs, b3, nullptr, omax + 2 * DD, 0);

  k_head<<<1, 384, 0, stream>>>(omax, linW, linb, out);
}